// Round 12
// baseline (5496.966 us; speedup 1.0000x reference)
//
#include <hip/hip_runtime.h>
#include <math.h>

// Problem constants
constexpr int N = 1024, B = 64, T = 12, HOR = 12, H = 64, E = 8;
constexpr size_t NBH = 4194304;  // 65536 * 64

// Row index convention for all state arrays: grow = b*1024 + n  (b = grow>>10)
// Workspace layout (float units)
constexpr size_t A_off   = 0;                      // [1024][1024] fp32 A
constexpr size_t Pxy_off = 1048576;                // [2][1024][1536] fp32 (n-major)
constexpr size_t h_off   = Pxy_off + 3145728;      // [65536][64] fp32
constexpr size_t Ph_off  = h_off + NBH;            // ushort[2][65536][64] fp16 (precompute: S2 partials alias)
constexpr size_t zh_off  = Ph_off + 2 * NBH;       // [65536][64] fp32 (precompute: AspL alias)
constexpr size_t r_off   = zh_off + NBH;           // [65536][64] fp32 (precompute: AspR alias)
constexpr size_t go_off  = r_off + NBH;            // [65536] fp32
constexpr size_t A2_off  = go_off + 65536;         // ushort[2048][1024]
constexpr size_t Bth_off = A2_off + 1048576;       // ushort[4224][1024] (rows 4096..4159 = go)
constexpr size_t Btz_off = Bth_off + 2162688;      // ushort[4096][1024]
constexpr size_t xyK_off = Btz_off + 2097152;      // ushort[1536][1024]
constexpr size_t Pgo_off = xyK_off + 786432;       // [2][1024][64] fp32
constexpr size_t wp_off  = Pgo_off + 131072;       // weight panels (ushort)

typedef __attribute__((ext_vector_type(8))) short short8;
typedef _Float16 half8 __attribute__((ext_vector_type(8)));
typedef __attribute__((ext_vector_type(4))) float f32x4;

__device__ __forceinline__ unsigned f2bf(float x) {
  unsigned u = __float_as_uint(x);
  return (u + 0x7fffu + ((u >> 16) & 1u)) >> 16;   // RNE
}
__device__ __forceinline__ float bf2f(unsigned h) {
  return __uint_as_float(h << 16);
}
__device__ __forceinline__ ushort f2h(float x) {
  _Float16 h = (_Float16)x;
  ushort u;
  __builtin_memcpy(&u, &h, 2);
  return u;
}
__device__ __forceinline__ void split4(float4 v, uint2& hi, uint2& lo) {
  unsigned h0 = f2bf(v.x), h1 = f2bf(v.y), h2 = f2bf(v.z), h3 = f2bf(v.w);
  unsigned l0 = f2bf(v.x - bf2f(h0)), l1 = f2bf(v.y - bf2f(h1));
  unsigned l2 = f2bf(v.z - bf2f(h2)), l3 = f2bf(v.w - bf2f(h3));
  hi.x = (h0 & 0xffffu) | (h1 << 16); hi.y = (h2 & 0xffffu) | (h3 << 16);
  lo.x = (l0 & 0xffffu) | (l1 << 16); lo.y = (l2 & 0xffffu) | (l3 << 16);
}

typedef const __attribute__((address_space(1))) void gas_t;
typedef __attribute__((address_space(3))) void las_t;

// ---------------------------------------------------------------------------
// A = softmax(relu(emb @ emb^T)) row-wise. One block per row.
// ---------------------------------------------------------------------------
__global__ __launch_bounds__(256) void build_A(const float* __restrict__ emb,
                                               float* __restrict__ A) {
  __shared__ float sE[N * E];
  __shared__ float sv[N];
  __shared__ float rmax[4], rsum[4];
  const int i = blockIdx.x;
  for (int idx = threadIdx.x; idx < N * E / 4; idx += 256)
    ((float4*)sE)[idx] = ((const float4*)emb)[idx];
  __syncthreads();
  float ei[E];
#pragma unroll
  for (int e = 0; e < E; ++e) ei[e] = sE[i * E + e];
  float mymax = 0.f;
  for (int j = threadIdx.x; j < N; j += 256) {
    float d = 0.f;
#pragma unroll
    for (int e = 0; e < E; ++e) d = fmaf(ei[e], sE[j * E + e], d);
    d = fmaxf(d, 0.f);
    sv[j] = d;
    mymax = fmaxf(mymax, d);
  }
  for (int off = 32; off; off >>= 1) mymax = fmaxf(mymax, __shfl_down(mymax, off));
  const int wid = threadIdx.x >> 6, lid = threadIdx.x & 63;
  if (lid == 0) rmax[wid] = mymax;
  __syncthreads();
  const float m = fmaxf(fmaxf(rmax[0], rmax[1]), fmaxf(rmax[2], rmax[3]));
  float mysum = 0.f;
  for (int j = threadIdx.x; j < N; j += 256) {
    float ev = expf(sv[j] - m);
    sv[j] = ev;
    mysum += ev;
  }
  for (int off = 32; off; off >>= 1) mysum += __shfl_down(mysum, off);
  if (lid == 0) rsum[wid] = mysum;
  __syncthreads();
  const float inv = 1.f / (rsum[0] + rsum[1] + rsum[2] + rsum[3]);
  for (int j = threadIdx.x; j < N; j += 256) A[i * N + j] = sv[j] * inv;
}

// ---------------------------------------------------------------------------
// Split-pack A for the exact S2 gemm: L=(hi,lo,hi), R=(hi,hi,lo) K-triples.
// ---------------------------------------------------------------------------
__global__ __launch_bounds__(256) void pack_split_S(const float* __restrict__ A,
                                                    ushort* __restrict__ L,
                                                    ushort* __restrict__ R) {
  __shared__ float tile[32][33];
  const int bx = blockIdx.x * 32;
  const int by = blockIdx.y * 32;
  const int tx = threadIdx.x & 31;
  const int tg = threadIdx.x >> 5;
#pragma unroll
  for (int p = 0; p < 4; ++p) {
    int ty = tg * 4 + p;
    tile[ty][tx] = A[(size_t)(by + ty) * 1024 + bx + tx];
  }
  __syncthreads();
#pragma unroll
  for (int p = 0; p < 4; ++p) {
    int ty = tg * 4 + p;
    float v = tile[ty][tx];
    unsigned h = f2bf(v);
    unsigned l = f2bf(v - bf2f(h));
    size_t lb = (size_t)(by + ty) * 3072 + 3 * (bx + tx);
    L[lb + 0] = (ushort)h; L[lb + 1] = (ushort)l; L[lb + 2] = (ushort)h;
    float w = tile[tx][ty];
    unsigned hh = f2bf(w);
    unsigned ll = f2bf(w - bf2f(hh));
    size_t rbi = (size_t)(bx + ty) * 3072 + 3 * (by + tx);
    R[rbi + 0] = (ushort)hh; R[rbi + 1] = (ushort)hh; R[rbi + 2] = (ushort)ll;
  }
}

// ---------------------------------------------------------------------------
// fp32 -> bf16 bulk convert (A2 rows 0..1023 = bf16(A))
// ---------------------------------------------------------------------------
__global__ __launch_bounds__(256) void conv_bf16(const float* __restrict__ src,
                                                 ushort* __restrict__ dst) {
  int i = blockIdx.x * 256 + threadIdx.x;
  float4 v = ((const float4*)src)[i];
  ushort4 o;
  o.x = (ushort)f2bf(v.x); o.y = (ushort)f2bf(v.y);
  o.z = (ushort)f2bf(v.z); o.w = (ushort)f2bf(v.w);
  ((ushort4*)dst)[i] = o;
}

// ---------------------------------------------------------------------------
// x/ycov -> bf16 K-major: dst[(off + t*64 + b)][n] = bf16(src[b][t][n])
// ---------------------------------------------------------------------------
__global__ __launch_bounds__(256) void conv_xyK(const float* __restrict__ src,
                                                ushort* __restrict__ dst, int off) {
  int id = blockIdx.x * 256 + threadIdx.x;
  int tb = id >> 10, n = id & 1023;
  int tt = tb >> 6, b = tb & 63;
  dst[(size_t)(off + tb) * 1024 + n] = (ushort)f2bf(src[((size_t)b * T + tt) * 1024 + n]);
}

// ---------------------------------------------------------------------------
// Pre-split s=0 (h-part) weights into panel-major bf16 hi/lo.
// ---------------------------------------------------------------------------
__global__ __launch_bounds__(256) void pack_Wbf(const float* __restrict__ W,
                                                ushort* __restrict__ out,
                                                int CIN, int NC, int xoff) {
  int idx = blockIdx.x * 256 + threadIdx.x;
  int total = 2 * NC * 32;
  if (idx >= total) return;
  int kk = idx & 31;
  int rest = idx >> 5;
  int col = rest % NC;
  int half = rest / NC;
  float v = W[(size_t)(xoff + half * 32 + kk) * NC + col];
  unsigned hi = f2bf(v);
  unsigned lo = f2bf(v - bf2f(hi));
  size_t base = (size_t)(half * 2) * NC * 32;
  out[base + (size_t)col * 32 + kk] = (ushort)hi;
  out[base + (size_t)NC * 32 + (size_t)col * 32 + kk] = (ushort)lo;
}

// ---------------------------------------------------------------------------
// Pack s=1,2 (Ph-part) weights into panel-major fp16.
// ---------------------------------------------------------------------------
__global__ __launch_bounds__(256) void pack_W16(const float* __restrict__ W,
                                                ushort* __restrict__ out,
                                                int CIN, int NC, int xoff) {
  int idx = blockIdx.x * 256 + threadIdx.x;
  int total = 2 * 2 * NC * 32;
  if (idx >= total) return;
  int kk = idx & 31;
  int rest = idx >> 5;
  int col = rest % NC;
  rest /= NC;
  int half = rest & 1;
  int s1 = rest >> 1;
  int s = s1 + 1;
  float v = W[(size_t)(s * CIN + xoff + half * 32 + kk) * NC + col];
  out[(size_t)(s1 * 2 + half) * NC * 32 + (size_t)col * 32 + kk] = f2h(v);
}

// ---------------------------------------------------------------------------
// S2 partials: split-K=4 of the split-bf16 A@A gemm (K=3072 interleaved).
// ---------------------------------------------------------------------------
__global__ __launch_bounds__(256) void gemm_s2p(
    const ushort* __restrict__ L, const ushort* __restrict__ R,
    float* __restrict__ P) {
  __shared__ ushort As[128 * 32];
  __shared__ ushort Bs[128 * 32];
  const int t = threadIdx.x;
  const int wave = t >> 6, lane = t & 63;
  const int bm = blockIdx.y * 128, bn = blockIdx.x * 128;
  const int wm = (wave & 1) * 64, wn = (wave >> 1) * 64;
  float* Pz = P + (size_t)blockIdx.z * 1048576;
  const int kbase = blockIdx.z * 768;

  const ushort* aSrc[2]; const ushort* bSrc[2];
  ushort* aDst[2]; ushort* bDst[2];
#pragma unroll
  for (int u = 0; u < 2; ++u) {
    int idx = wave * 128 + u * 64 + lane;
    int row = idx >> 2;
    int kq = (idx & 3) * 8;
    aSrc[u] = L + (size_t)(bm + row) * 3072 + kq;
    bSrc[u] = R + (size_t)(bn + row) * 3072 + kq;
    aDst[u] = &As[(wave * 128 + u * 64) * 8];
    bDst[u] = &Bs[(wave * 128 + u * 64) * 8];
  }
  const int lr = lane & 15;
  const int lk = (lane >> 4) * 8;
  f32x4 acc[4][4];
#pragma unroll
  for (int i = 0; i < 4; ++i)
#pragma unroll
    for (int j = 0; j < 4; ++j) acc[i][j] = {0.f, 0.f, 0.f, 0.f};

  for (int k0 = kbase; k0 < kbase + 768; k0 += 32) {
#pragma unroll
    for (int u = 0; u < 2; ++u) {
      __builtin_amdgcn_global_load_lds((gas_t*)(aSrc[u] + k0), (las_t*)aDst[u], 16, 0, 0);
      __builtin_amdgcn_global_load_lds((gas_t*)(bSrc[u] + k0), (las_t*)bDst[u], 16, 0, 0);
    }
    __syncthreads();
    short8 a[4], b[4];
#pragma unroll
    for (int i = 0; i < 4; ++i) a[i] = *(const short8*)&As[(wm + i * 16 + lr) * 32 + lk];
#pragma unroll
    for (int j = 0; j < 4; ++j) b[j] = *(const short8*)&Bs[(wn + j * 16 + lr) * 32 + lk];
#pragma unroll
    for (int i = 0; i < 4; ++i)
#pragma unroll
      for (int j = 0; j < 4; ++j)
        acc[i][j] = __builtin_amdgcn_mfma_f32_16x16x32_bf16(a[i], b[j], acc[i][j], 0, 0, 0);
    __syncthreads();
  }
  const int cr = (lane >> 4) * 4;
  const int cc = lane & 15;
#pragma unroll
  for (int i = 0; i < 4; ++i)
#pragma unroll
    for (int j = 0; j < 4; ++j) {
      int gm = bm + wm + i * 16 + cr;
      int gn = bn + wn + j * 16 + cc;
#pragma unroll
      for (int r = 0; r < 4; ++r)
        Pz[(size_t)(gm + r) * 1024 + gn] = acc[i][j][r];
    }
}

// ---------------------------------------------------------------------------
// Combine S2 partials: v = 2*sum - I, write bf16 into A2 rows 1024..2047.
// ---------------------------------------------------------------------------
__global__ __launch_bounds__(256) void comb_s2(const float* __restrict__ P,
                                               ushort* __restrict__ A2) {
  int idx = blockIdx.x * 256 + threadIdx.x;
  float4 a = ((const float4*)P)[idx];
  float4 b = ((const float4*)(P + 1048576))[idx];
  float4 c = ((const float4*)(P + 2097152))[idx];
  float4 d = ((const float4*)(P + 3145728))[idx];
  int base = idx << 2;
  int m = base >> 10, c0 = base & 1023;
  float v0 = 2.f * (a.x + b.x + c.x + d.x) - (m == c0 + 0 ? 1.f : 0.f);
  float v1 = 2.f * (a.y + b.y + c.y + d.y) - (m == c0 + 1 ? 1.f : 0.f);
  float v2 = 2.f * (a.z + b.z + c.z + d.z) - (m == c0 + 2 ? 1.f : 0.f);
  float v3 = 2.f * (a.w + b.w + c.w + d.w) - (m == c0 + 3 ? 1.f : 0.f);
  ushort4 o;
  o.x = (ushort)f2bf(v0); o.y = (ushort)f2bf(v1);
  o.z = (ushort)f2bf(v2); o.w = (ushort)f2bf(v3);
  ((ushort4*)(A2 + 1048576))[idx] = o;
}

// ---------------------------------------------------------------------------
// Propagation GEMM, R12: LDS-FREE register-direct form.
// C[2048][cols] = A2 @ Bt^T, both operands bf16 K-major.
// Block = 64m x 128n, 4 waves as (wm = (w&1)*32, wn = (w>>1)*64).
// Each lane loads its MFMA fragments straight from global (16 B/lane,
// natural K-major fragment layout), double register prefetch, NO barriers.
// CMODE 0: C1f fp32 row-major stride n1. CMODE 1: C1h fp16 state layout,
// 1-D grid with XCD swizzle. Fold cols >= n1 -> C2 (fp32).
// ---------------------------------------------------------------------------
template <int CMODE>
__global__ __launch_bounds__(256) void gemm_bt(
    const ushort* __restrict__ A2, const ushort* __restrict__ Bt, int n1,
    ushort* __restrict__ C1h, float* __restrict__ C1f, float* __restrict__ C2) {
  const int t = threadIdx.x;
  const int wave = t >> 6, lane = t & 63;
  int bxi, byi;
  if (CMODE == 0) {
    bxi = blockIdx.x; byi = blockIdx.y;
  } else {
    int lin = blockIdx.x;
    if (lin < 1024) {
      bxi = (lin & 7) * 4 + ((lin >> 3) & 3);   // XCD x owns n-tiles 4x..4x+3
      byi = lin >> 5;
    } else {
      bxi = 32; byi = lin - 1024;               // decoder go-fold column
    }
  }
  const int bm = byi * 64, bn = bxi * 128;
  const int wm = (wave & 1) * 32, wn = (wave >> 1) * 64;
  const int lr = lane & 15;
  const int lk8 = (lane >> 4) * 8;

  // fragment row pointers (each lane: 16 bf16 = one 16B chunk per frag)
  const ushort* aRow[2];
#pragma unroll
  for (int i = 0; i < 2; ++i)
    aRow[i] = A2 + (size_t)(bm + wm + i * 16 + lr) * 1024 + lk8;
  const ushort* bRow[4];
#pragma unroll
  for (int j = 0; j < 4; ++j)
    bRow[j] = Bt + (size_t)(bn + wn + j * 16 + lr) * 1024 + lk8;

  f32x4 acc[2][4];
#pragma unroll
  for (int i = 0; i < 2; ++i)
#pragma unroll
    for (int j = 0; j < 4; ++j) acc[i][j] = {0.f, 0.f, 0.f, 0.f};

  short8 a0[2], b0[4], a1[2], b1[4];
#pragma unroll
  for (int i = 0; i < 2; ++i) a0[i] = *(const short8*)(aRow[i]);
#pragma unroll
  for (int j = 0; j < 4; ++j) b0[j] = *(const short8*)(bRow[j]);

  // K = 1024, 32 k-steps of 32, unrolled x2 with register double-prefetch
#pragma unroll 4
  for (int k0 = 0; k0 < 1024; k0 += 64) {
#pragma unroll
    for (int i = 0; i < 2; ++i) a1[i] = *(const short8*)(aRow[i] + k0 + 32);
#pragma unroll
    for (int j = 0; j < 4; ++j) b1[j] = *(const short8*)(bRow[j] + k0 + 32);
#pragma unroll
    for (int i = 0; i < 2; ++i)
#pragma unroll
      for (int j = 0; j < 4; ++j)
        acc[i][j] = __builtin_amdgcn_mfma_f32_16x16x32_bf16(a0[i], b0[j], acc[i][j], 0, 0, 0);
    if (k0 + 64 < 1024) {
#pragma unroll
      for (int i = 0; i < 2; ++i) a0[i] = *(const short8*)(aRow[i] + k0 + 64);
#pragma unroll
      for (int j = 0; j < 4; ++j) b0[j] = *(const short8*)(bRow[j] + k0 + 64);
    }
#pragma unroll
    for (int i = 0; i < 2; ++i)
#pragma unroll
      for (int j = 0; j < 4; ++j)
        acc[i][j] = __builtin_amdgcn_mfma_f32_16x16x32_bf16(a1[i], b1[j], acc[i][j], 0, 0, 0);
  }

  const int cr = (lane >> 4) * 4;
  const int cc = lane & 15;
#pragma unroll
  for (int i = 0; i < 2; ++i) {
#pragma unroll
    for (int j = 0; j < 4; ++j) {
      int gm = bm + wm + i * 16 + cr;
      int gn = bn + wn + j * 16 + cc;
      if (gn < n1) {
        if (CMODE == 0) {
          float* p = C1f + (size_t)gm * n1 + gn;
#pragma unroll
          for (int r = 0; r < 4; ++r) p[(size_t)r * n1] = acc[i][j][r];
        } else {
          int half = gm >> 10, nn = gm & 1023;
          ushort* p = C1h + (size_t)half * NBH +
                      ((size_t)(gn >> 6) * 1024 + nn) * 64 + (gn & 63);
#pragma unroll
          for (int r = 0; r < 4; ++r) p[(size_t)r * 64] = f2h(acc[i][j][r]);
        }
      } else if (C2 != nullptr && gn < n1 + 64) {
        float* p = C2 + (size_t)gm * 64 + (gn - n1);
#pragma unroll
        for (int r = 0; r < 4; ++r) p[(size_t)r * 64] = acc[i][j][r];
      }
    }
  }
}

// ---------------------------------------------------------------------------
// Gate: zr = sigmoid( s0-GEMM(split-bf16 exact h) + s1,2-GEMM(fp16 Ph, f16 MFMA)
//                     + exact fp32 x-terms + bias ). Writes zh, r, Btz.
// ---------------------------------------------------------------------------
template <int NX>
__global__ __launch_bounds__(256, 4) void gate_mfma(
    const float* __restrict__ hmat, const ushort* __restrict__ Ph16,
    const ushort* __restrict__ Wbf, const ushort* __restrict__ W16,
    const float* __restrict__ Wf, const float* __restrict__ bias,
    const float* __restrict__ xb0, int xbs0, const float* __restrict__ xp0, int xs0,
    const float* __restrict__ xb1, int xbs1, const float* __restrict__ xp1, int xs1,
    float* __restrict__ zh, float* __restrict__ rbuf, ushort* __restrict__ Btz) {
  constexpr int CIN = NX + 64;
  __shared__ ushort smem[12288];
  ushort* Ah = smem;
  ushort* Al = smem + 2048;
  ushort* Bh = smem + 4096;
  ushort* Bl = smem + 8192;
  ushort* A16 = smem;
  ushort* B16 = smem + 4096;
  ushort* transT = smem;
  __shared__ float sxv[3][2][64];
  __shared__ float sWx[3][2][128];
  const int t = threadIdx.x;
  const int wave = t >> 6, lane = t & 63;
  const int bm = blockIdx.x * 64;
  const int wm = (wave & 1) * 32, wn = (wave >> 1) * 64;
  const int lr = lane & 15, lk = (lane >> 4) * 8;

  if (t < 64) {
    int grow = bm + t;
    int n = grow & 1023, b = grow >> 10;
    sxv[0][0][t] = xb0[(size_t)b * xbs0 + n];
    sxv[1][0][t] = xp0[(size_t)n * xs0 + b];
    sxv[2][0][t] = xp0[(size_t)1024 * xs0 + (size_t)n * xs0 + b];
    if (NX == 2) {
      sxv[0][1][t] = xb1[(size_t)b * xbs1 + n];
      sxv[1][1][t] = xp1[(size_t)n * xs1 + b];
      sxv[2][1][t] = xp1[(size_t)1024 * xs1 + (size_t)n * xs1 + b];
    }
  } else if (t < 192) {
    int col = t - 64;
#pragma unroll
    for (int s = 0; s < 3; ++s)
#pragma unroll
      for (int f = 0; f < NX; ++f)
        sWx[s][f][col] = Wf[(size_t)(s * CIN + f) * 128 + col];
  }

  int arow[2], ajq[2];
#pragma unroll
  for (int p = 0; p < 2; ++p) {
    int f = p * 256 + t;
    arow[p] = f >> 3;
    ajq[p] = (f & 7) * 4;
  }
  const int hrow = t >> 2, hjq = (t & 3) * 8;

  float4 pf[2];
#pragma unroll
  for (int p = 0; p < 2; ++p)
    pf[p] = *(const float4*)(hmat + (size_t)(bm + arow[p]) * 64 + ajq[p]);
  uint4 px;

  f32x4 acc[2][4];
#pragma unroll
  for (int i = 0; i < 2; ++i)
#pragma unroll
    for (int j = 0; j < 4; ++j) acc[i][j] = {0.f, 0.f, 0.f, 0.f};

  // ---- phase 1: s=0, exact split-bf16, 2 halves ----
#pragma unroll
  for (int half = 0; half < 2; ++half) {
#pragma unroll
    for (int p = 0; p < 2; ++p) {
      uint2 hi, lo;
      split4(pf[p], hi, lo);
      *(uint2*)&Ah[arow[p] * 32 + ajq[p]] = hi;
      *(uint2*)&Al[arow[p] * 32 + ajq[p]] = lo;
    }
    const ushort* wph = Wbf + (size_t)(half * 2) * (128 * 32);
    const ushort* wpl = wph + 128 * 32;
#pragma unroll
    for (int u = 0; u < 2; ++u) {
      int idx = wave * 128 + u * 64 + lane;
      __builtin_amdgcn_global_load_lds((gas_t*)(wph + idx * 8), (las_t*)&Bh[idx * 8], 16, 0, 0);
      __builtin_amdgcn_global_load_lds((gas_t*)(wpl + idx * 8), (las_t*)&Bl[idx * 8], 16, 0, 0);
    }
    __syncthreads();
    if (half == 0) {
#pragma unroll
      for (int p = 0; p < 2; ++p)
        pf[p] = *(const float4*)(hmat + (size_t)(bm + arow[p]) * 64 + 32 + ajq[p]);
    } else {
      px = *(const uint4*)(Ph16 + (size_t)(bm + hrow) * 64 + hjq);
    }
    short8 ah[2], al[2], bh[4], bl[4];
#pragma unroll
    for (int i = 0; i < 2; ++i) {
      ah[i] = *(const short8*)&Ah[(wm + i * 16 + lr) * 32 + lk];
      al[i] = *(const short8*)&Al[(wm + i * 16 + lr) * 32 + lk];
    }
#pragma unroll
    for (int j = 0; j < 4; ++j) {
      bh[j] = *(const short8*)&Bh[(wn + j * 16 + lr) * 32 + lk];
      bl[j] = *(const short8*)&Bl[(wn + j * 16 + lr) * 32 + lk];
    }
#pragma unroll
    for (int i = 0; i < 2; ++i)
#pragma unroll
      for (int j = 0; j < 4; ++j) {
        acc[i][j] = __builtin_amdgcn_mfma_f32_16x16x32_bf16(ah[i], bh[j], acc[i][j], 0, 0, 0);
        acc[i][j] = __builtin_amdgcn_mfma_f32_16x16x32_bf16(al[i], bh[j], acc[i][j], 0, 0, 0);
        acc[i][j] = __builtin_amdgcn_mfma_f32_16x16x32_bf16(ah[i], bl[j], acc[i][j], 0, 0, 0);
      }
    __syncthreads();
  }

  // ---- phase 2: s=1,2 fp16 Ph, single f16 MFMA ----
  for (int it = 0; it < 4; ++it) {
    const int s1 = it >> 1, half = it & 1;
    *(uint4*)&A16[hrow * 32 + hjq] = px;
    const ushort* w16 = W16 + (size_t)(s1 * 2 + half) * (128 * 32);
#pragma unroll
    for (int u = 0; u < 2; ++u) {
      int idx = wave * 128 + u * 64 + lane;
      __builtin_amdgcn_global_load_lds((gas_t*)(w16 + idx * 8), (las_t*)&B16[idx * 8], 16, 0, 0);
    }
    __syncthreads();
    if (it < 3) {
      const int nit = it + 1;
      const ushort* src = Ph16 + (size_t)(nit >> 1) * NBH;
      px = *(const uint4*)(src + (size_t)(bm + hrow) * 64 + (nit & 1) * 32 + hjq);
    }
    half8 a16[2], b16[4];
#pragma unroll
    for (int i = 0; i < 2; ++i)
      a16[i] = *(const half8*)&A16[(wm + i * 16 + lr) * 32 + lk];
#pragma unroll
    for (int j = 0; j < 4; ++j)
      b16[j] = *(const half8*)&B16[(wn + j * 16 + lr) * 32 + lk];
#pragma unroll
    for (int i = 0; i < 2; ++i)
#pragma unroll
      for (int j = 0; j < 4; ++j)
        acc[i][j] = __builtin_amdgcn_mfma_f32_16x16x32_f16(a16[i], b16[j], acc[i][j], 0, 0, 0);
    __syncthreads();
  }

  const int cr = (lane >> 4) * 4;
  const int cc = lane & 15;
#pragma unroll
  for (int i = 0; i < 2; ++i) {
#pragma unroll
    for (int j = 0; j < 4; ++j) {
      int col = wn + j * 16 + cc;
      float bcol = bias[col];
#pragma unroll
      for (int r = 0; r < 4; ++r) {
        int rowl = wm + i * 16 + cr + r;
        int grow = bm + rowl;
        float v = acc[i][j][r] + bcol;
#pragma unroll
        for (int s = 0; s < 3; ++s)
#pragma unroll
          for (int f = 0; f < NX; ++f)
            v = fmaf(sxv[s][f][rowl], sWx[s][f][col], v);
        float sig = 1.f / (1.f + expf(-v));
        if (col < 64) {
          float zv = sig * hmat[(size_t)grow * 64 + col];
          zh[(size_t)grow * 64 + col] = zv;
          transT[col * 72 + rowl] = (ushort)f2bf(zv);
        } else {
          rbuf[(size_t)grow * 64 + col - 64] = sig;
        }
      }
    }
  }
  __syncthreads();
  const int bq = bm >> 10, nb = bm & 1023;
  for (int idx = t; idx < 512; idx += 256) {
    int j = idx >> 3, ch = idx & 7;
    uint4 v = *(const uint4*)&transT[j * 72 + ch * 8];
    *(uint4*)(Btz + (((size_t)(bq * 64 + j)) << 10) + nb + ch * 8) = v;
  }
}

// ---------------------------------------------------------------------------
// Update: hc = tanh(s0-GEMM(split zh) + s1,2-GEMM(fp16 Pzh) + x-terms + b);
// h = r*h + (1-r)*hc. PROJ=1 fuses go-projection.
// ---------------------------------------------------------------------------
template <int NX, int PROJ>
__global__ __launch_bounds__(256, 4) void upd_mfma(
    float* __restrict__ hmat, const float* __restrict__ zhb, const ushort* __restrict__ Pzh16,
    const ushort* __restrict__ Wbf, const ushort* __restrict__ W16,
    const float* __restrict__ Wf, const float* __restrict__ bias,
    const float* __restrict__ xb0, int xbs0, const float* __restrict__ xp0, int xs0,
    const float* __restrict__ xb1, int xbs1, const float* __restrict__ xp1, int xs1,
    const float* __restrict__ rbuf, ushort* __restrict__ Bth,
    const float* __restrict__ pW, const float* __restrict__ pb,
    float* __restrict__ gobuf, float* __restrict__ outp, int tstep) {
  constexpr int CIN = NX + 64;
  __shared__ ushort smem[8192];
  ushort* Ah = smem;
  ushort* Al = smem + 2048;
  ushort* Bh = smem + 4096;
  ushort* Bl = smem + 6144;
  ushort* A16 = smem;
  ushort* B16 = smem + 4096;
  ushort* transT = smem;
  __shared__ float sxv[3][2][64];
  __shared__ float sWx[3][2][64];
  __shared__ float part[2][64];
  const int t = threadIdx.x;
  const int wave = t >> 6, lane = t & 63;
  const int bm = blockIdx.x * 64;
  const int wm = (wave & 1) * 32, wn = (wave >> 1) * 32;
  const int lr = lane & 15, lk = (lane >> 4) * 8;

  if (t < 64) {
    int grow = bm + t;
    int n = grow & 1023, b = grow >> 10;
    sxv[0][0][t] = xb0[(size_t)b * xbs0 + n];
    sxv[1][0][t] = xp0[(size_t)n * xs0 + b];
    sxv[2][0][t] = xp0[(size_t)1024 * xs0 + (size_t)n * xs0 + b];
    if (NX == 2) {
      sxv[0][1][t] = xb1[(size_t)b * xbs1 + n];
      sxv[1][1][t] = xp1[(size_t)n * xs1 + b];
      sxv[2][1][t] = xp1[(size_t)1024 * xs1 + (size_t)n * xs1 + b];
    }
  } else if (t < 128) {
    int col = t - 64;
#pragma unroll
    for (int s = 0; s < 3; ++s)
#pragma unroll
      for (int f = 0; f < NX; ++f)
        sWx[s][f][col] = Wf[(size_t)(s * CIN + f) * 64 + col];
  }

  int arow[2], ajq[2];
#pragma unroll
  for (int p = 0; p < 2; ++p) {
    int f = p * 256 + t;
    arow[p] = f >> 3;
    ajq[p] = (f & 7) * 4;
  }
  const int hrow = t >> 2, hjq = (t & 3) * 8;

  float4 pf[2];
#pragma unroll
  for (int p = 0; p < 2; ++p)
    pf[p] = *(const float4*)(zhb + (size_t)(bm + arow[p]) * 64 + ajq[p]);
  uint4 px;

  f32x4 acc[2][2];
#pragma unroll
  for (int i = 0; i < 2; ++i)
#pragma unroll
    for (int j = 0; j < 2; ++j) acc[i][j] = {0.f, 0.f, 0.f, 0.f};

  // ---- phase 1: s=0 exact split ----
#pragma unroll
  for (int half = 0; half < 2; ++half) {
#pragma unroll
    for (int p = 0; p < 2; ++p) {
      uint2 hi, lo;
      split4(pf[p], hi, lo);
      *(uint2*)&Ah[arow[p] * 32 + ajq[p]] = hi;
      *(uint2*)&Al[arow[p] * 32 + ajq[p]] = lo;
    }
    const ushort* wph = Wbf + (size_t)(half * 2) * (64 * 32);
    const ushort* wpl = wph + 64 * 32;
    {
      int idx = wave * 64 + lane;
      __builtin_amdgcn_global_load_lds((gas_t*)(wph + idx * 8), (las_t*)&Bh[idx * 8], 16, 0, 0);
      __builtin_amdgcn_global_load_lds((gas_t*)(wpl + idx * 8), (las_t*)&Bl[idx * 8], 16, 0, 0);
    }
    __syncthreads();
    if (half == 0) {
#pragma unroll
      for (int p = 0; p < 2; ++p)
        pf[p] = *(const float4*)(zhb + (size_t)(bm + arow[p]) * 64 + 32 + ajq[p]);
    } else {
      px = *(const uint4*)(Pzh16 + (size_t)(bm + hrow) * 64 + hjq);
    }
    short8 ah[2], al[2], bh[2], bl[2];
#pragma unroll
    for (int i = 0; i < 2; ++i) {
      ah[i] = *(const short8*)&Ah[(wm + i * 16 + lr) * 32 + lk];
      al[i] = *(const short8*)&Al[(wm + i * 16 + lr) * 32 + lk];
    }
#pragma unroll
    for (int j = 0; j < 2; ++j) {
      bh[j] = *(const short8*)&Bh[(wn + j * 16 + lr) * 32 + lk];
      bl[j] = *(const short8*)&Bl[(wn + j * 16 + lr) * 32 + lk];
    }
#pragma unroll
    for (int i = 0; i < 2; ++i)
#pragma unroll
      for (int j = 0; j < 2; ++j) {
        acc[i][j] = __builtin_amdgcn_mfma_f32_16x16x32_bf16(ah[i], bh[j], acc[i][j], 0, 0, 0);
        acc[i][j] = __builtin_amdgcn_mfma_f32_16x16x32_bf16(al[i], bh[j], acc[i][j], 0, 0, 0);
        acc[i][j] = __builtin_amdgcn_mfma_f32_16x16x32_bf16(ah[i], bl[j], acc[i][j], 0, 0, 0);
      }
    __syncthreads();
  }

  // ---- phase 2: s=1,2 fp16 ----
  for (int it = 0; it < 4; ++it) {
    const int s1 = it >> 1, half = it & 1;
    *(uint4*)&A16[hrow * 32 + hjq] = px;
    const ushort* w16 = W16 + (size_t)(s1 * 2 + half) * (64 * 32);
    {
      int idx = wave * 64 + lane;
      __builtin_amdgcn_global_load_lds((gas_t*)(w16 + idx * 8), (las_t*)&B16[idx * 8], 16, 0, 0);
    }
    __syncthreads();
    if (it < 3) {
      const int nit = it + 1;
      const ushort* src = Pzh16 + (size_t)(nit >> 1) * NBH;
      px = *(const uint4*)(src + (size_t)(bm + hrow) * 64 + (nit & 1) * 32 + hjq);
    }
    half8 a16[2], b16[2];
#pragma unroll
    for (int i = 0; i < 2; ++i)
      a16[i] = *(const half8*)&A16[(wm + i * 16 + lr) * 32 + lk];
#pragma unroll
    for (int j = 0; j < 2; ++j)
      b16[j] = *(const half8*)&B16[(wn + j * 16 + lr) * 32 + lk];
#pragma unroll
    for (int i = 0; i < 2; ++i)
#pragma unroll
      for (int j = 0; j < 2; ++j)
        acc[i][j] = __builtin_amdgcn_mfma_f32_16x16x32_f16(a16[i], b16[j], acc[i][j], 0, 0, 0);
    __syncthreads();
  }

  const int cr = (lane >> 4) * 4;
  const int cc = lane & 15;
  float psv[2][4];
#pragma unroll
  for (int i = 0; i < 2; ++i)
#pragma unroll
    for (int r = 0; r < 4; ++r) psv[i][r] = 0.f;

#pragma unroll
  for (int i = 0; i < 2; ++i) {
#pragma unroll
    for (int j = 0; j < 2; ++j) {
      int col = wn + j * 16 + cc;
      float bcol = bias[col];
      float pwc = PROJ ? pW[col] : 0.f;
#pragma unroll
      for (int r = 0; r < 4; ++r) {
        int rowl = wm + i * 16 + cr + r;
        int grow = bm + rowl;
        float v = acc[i][j][r] + bcol;
#pragma unroll
        for (int s = 0; s < 3; ++s)
#pragma unroll
          for (int f = 0; f < NX; ++f)
            v = fmaf(sxv[s][f][rowl], sWx[s][f][col], v);
        float hc = tanhf(v);
        size_t idx = (size_t)grow * 64 + col;
        float rr = rbuf[idx];
        float ho = hmat[idx];
        float o = rr * ho + (1.f - rr) * hc;
        hmat[idx] = o;
        transT[col * 72 + rowl] = (ushort)f2bf(o);
        if (PROJ) psv[i][r] += o * pwc;
      }
    }
  }
  if (PROJ) {
#pragma unroll
    for (int i = 0; i < 2; ++i)
#pragma unroll
      for (int r = 0; r < 4; ++r)
#pragma unroll
        for (int off = 8; off; off >>= 1)
          psv[i][r] += __shfl_down(psv[i][r], off, 16);
    if (cc == 0) {
#pragma unroll
      for (int i = 0; i < 2; ++i)
#pragma unroll
        for (int r = 0; r < 4; ++r)
          part[wn >> 5][wm + i * 16 + cr + r] = psv[i][r];
    }
  }
  __syncthreads();
  const int bq = bm >> 10, nb = bm & 1023;
  for (int idx = t; idx < 512; idx += 256) {
    int j = idx >> 3, ch = idx & 7;
    uint4 v = *(const uint4*)&transT[j * 72 + ch * 8];
    *(uint4*)(Bth + (((size_t)(bq * 64 + j)) << 10) + nb + ch * 8) = v;
  }
  if (PROJ && t < 64) {
    int grow = bm + t;
    int n = grow & 1023, b = grow >> 10;
    float g = part[0][t] + part[1][t] + pb[0];
    gobuf[grow] = g;
    outp[((size_t)b * HOR + tstep) * N + n] = g;
    Bth[((size_t)(4096 + b)) * 1024 + n] = (ushort)f2bf(g);
  }
}

// ---------------------------------------------------------------------------
extern "C" void kernel_launch(void* const* d_in, const int* in_sizes, int n_in,
                              void* d_out, int out_size, void* d_ws, size_t ws_size,
                              hipStream_t stream) {
  const float* x    = (const float*)d_in[0];
  const float* ycov = (const float*)d_in[1];
  const float* emb  = (const float*)d_in[2];
  const float* egW  = (const float*)d_in[3];
  const float* egb  = (const float*)d_in[4];
  const float* euW  = (const float*)d_in[5];
  const float* eub  = (const float*)d_in[6];
  const float* dgW  = (const float*)d_in[7];
  const float* dgb  = (const float*)d_in[8];
  const float* duW  = (const float*)d_in[9];
  const float* dub  = (const float*)d_in[10];
  const float* pW   = (const float*)d_in[11];
  const float* pb   = (const float*)d_in[12];
  float* out = (float*)d_out;
  float* ws  = (float*)d_ws;

  float* Amat = ws + A_off;
  float* Pxy  = ws + Pxy_off;
  float* hmat = ws + h_off;
  ushort* Ph16 = (ushort*)(ws + Ph_off);
  float* zh   = ws + zh_off;
  float* rb   = ws + r_off;
  float* gob  = ws + go_off;
  float* Pgo  = ws + Pgo_off;
  ushort* A2   = (ushort*)(ws + A2_off);
  ushort* Bth  = (ushort*)(ws + Bth_off);
  ushort* Btz  = (ushort*)(ws + Btz_off);
  ushort* xyK  = (ushort*)(ws + xyK_off);
  ushort* AspL = (ushort*)(ws + zh_off);
  ushort* AspR = (ushort*)(ws + r_off);
  float*  Pp   = ws + Ph_off;              // S2 partials alias (precompute only)
  ushort* WB   = (ushort*)(ws + wp_off);
  ushort* WbfGE = WB;
  ushort* WbfGD = WB + 16384;
  ushort* WbfUE = WB + 32768;
  ushort* WbfUD = WB + 40960;
  ushort* W16GE = WB + 49152;
  ushort* W16GD = WB + 65536;
  ushort* W16UE = WB + 81920;
  ushort* W16UD = WB + 90112;

  // ---- precompute ----
  build_A<<<N, 256, 0, stream>>>(emb, Amat);
  pack_split_S<<<dim3(32, 32), 256, 0, stream>>>(Amat, AspL, AspR);
  gemm_s2p<<<dim3(8, 8, 4), 256, 0, stream>>>(AspL, AspR, Pp);
  comb_s2<<<1024, 256, 0, stream>>>(Pp, A2);
  conv_bf16<<<1024, 256, 0, stream>>>(Amat, A2);
  conv_xyK<<<3072, 256, 0, stream>>>(x, xyK, 0);
  conv_xyK<<<3072, 256, 0, stream>>>(ycov, xyK, 768);
  pack_Wbf<<<32, 256, 0, stream>>>(egW, WbfGE, 65, 128, 1);
  pack_Wbf<<<32, 256, 0, stream>>>(dgW, WbfGD, 66, 128, 2);
  pack_Wbf<<<16, 256, 0, stream>>>(euW, WbfUE, 65, 64, 1);
  pack_Wbf<<<16, 256, 0, stream>>>(duW, WbfUD, 66, 64, 2);
  pack_W16<<<64, 256, 0, stream>>>(egW, W16GE, 65, 128, 1);
  pack_W16<<<64, 256, 0, stream>>>(dgW, W16GD, 66, 128, 2);
  pack_W16<<<32, 256, 0, stream>>>(euW, W16UE, 65, 64, 1);
  pack_W16<<<32, 256, 0, stream>>>(duW, W16UD, 66, 64, 2);
  gemm_bt<0><<<dim3(12, 32), 256, 0, stream>>>(A2, xyK, 1536, nullptr, Pxy, nullptr);
  (void)hipMemsetAsync(hmat, 0, NBH * sizeof(float), stream);
  (void)hipMemsetAsync(Ph16, 0, 2 * NBH * sizeof(ushort), stream);
  (void)hipMemsetAsync(gob, 0, 65536 * sizeof(float), stream);
  (void)hipMemsetAsync(Bth + (size_t)4096 * 1024, 0, 128 * 1024 * sizeof(ushort), stream);

  // ---- encoder ----
  for (int t = 0; t < T; ++t) {
    if (t > 0)  // t=0: h=0 so Ph=0 (memset)
      gemm_bt<1><<<1024, 256, 0, stream>>>(A2, Bth, 4096, Ph16, nullptr, nullptr);
    gate_mfma<1><<<1024, 256, 0, stream>>>(hmat, Ph16, WbfGE, W16GE, egW, egb,
                                           x + t * 1024, T * 1024, Pxy + t * 64, 1536,
                                           nullptr, 0, nullptr, 0, zh, rb, Btz);
    if (t > 0)  // t=0: zh = z*0 = 0, so P(zh)=0
      gemm_bt<1><<<1024, 256, 0, stream>>>(A2, Btz, 4096, Ph16, nullptr, nullptr);
    upd_mfma<1, 0><<<1024, 256, 0, stream>>>(hmat, zh, Ph16, WbfUE, W16UE, euW, eub,
                                             x + t * 1024, T * 1024, Pxy + t * 64, 1536,
                                             nullptr, 0, nullptr, 0, rb, Bth,
                                             nullptr, nullptr, nullptr, nullptr, 0);
  }

  // ---- decoder ----
  for (int t = 0; t < HOR; ++t) {
    gemm_bt<1><<<1056, 256, 0, stream>>>(A2, Bth, 4096, Ph16, nullptr, Pgo);
    gate_mfma<2><<<1024, 256, 0, stream>>>(hmat, Ph16, WbfGD, W16GD, dgW, dgb,
                                           gob, 1024, Pgo, 64,
                                           ycov + t * 1024, HOR * 1024,
                                           Pxy + 768 + t * 64, 1536, zh, rb, Btz);
    gemm_bt<1><<<1024, 256, 0, stream>>>(A2, Btz, 4096, Ph16, nullptr, nullptr);
    upd_mfma<2, 1><<<1024, 256, 0, stream>>>(hmat, zh, Ph16, WbfUD, W16UD, duW, dub,
                                             gob, 1024, Pgo, 64,
                                             ycov + t * 1024, HOR * 1024,
                                             Pxy + 768 + t * 64, 1536,
                                             rb, Bth, pW, pb, gob, out, t);
  }
}

// Round 13
// 2497.787 us; speedup vs baseline: 2.2007x; 2.2007x over previous
//
#include <hip/hip_runtime.h>
#include <math.h>

// Problem constants
constexpr int N = 1024, B = 64, T = 12, HOR = 12, H = 64, E = 8;
constexpr size_t NBH = 4194304;  // 65536 * 64

// Row index convention for all state arrays: grow = b*1024 + n  (b = grow>>10)
// Workspace layout (float units)
constexpr size_t A_off   = 0;                      // [1024][1024] fp32 A
constexpr size_t Pxy_off = 1048576;                // [2][1024][1536] fp32 (n-major)
constexpr size_t h_off   = Pxy_off + 3145728;      // [65536][64] fp32
constexpr size_t Ph_off  = h_off + NBH;            // ushort[2][65536][64] fp16 (precompute: S2 partials alias)
constexpr size_t zh_off  = Ph_off + 2 * NBH;       // [65536][64] fp32 (precompute: AspL alias)
constexpr size_t r_off   = zh_off + NBH;           // [65536][64] fp32 (precompute: AspR alias)
constexpr size_t go_off  = r_off + NBH;            // [65536] fp32
constexpr size_t A2_off  = go_off + 65536;         // ushort[2048][1024]
constexpr size_t Bth_off = A2_off + 1048576;       // ushort[4224][1024] (rows 4096..4159 = go)
constexpr size_t Btz_off = Bth_off + 2162688;      // ushort[4096][1024]
constexpr size_t xyK_off = Btz_off + 2097152;      // ushort[1536][1024]
constexpr size_t Pgo_off = xyK_off + 786432;       // [2][1024][64] fp32
constexpr size_t wp_off  = Pgo_off + 131072;       // weight panels (ushort)

typedef __attribute__((ext_vector_type(8))) short short8;
typedef _Float16 half8 __attribute__((ext_vector_type(8)));
typedef __attribute__((ext_vector_type(4))) float f32x4;

__device__ __forceinline__ unsigned f2bf(float x) {
  unsigned u = __float_as_uint(x);
  return (u + 0x7fffu + ((u >> 16) & 1u)) >> 16;   // RNE
}
__device__ __forceinline__ float bf2f(unsigned h) {
  return __uint_as_float(h << 16);
}
__device__ __forceinline__ ushort f2h(float x) {
  _Float16 h = (_Float16)x;
  ushort u;
  __builtin_memcpy(&u, &h, 2);
  return u;
}
__device__ __forceinline__ void split4(float4 v, uint2& hi, uint2& lo) {
  unsigned h0 = f2bf(v.x), h1 = f2bf(v.y), h2 = f2bf(v.z), h3 = f2bf(v.w);
  unsigned l0 = f2bf(v.x - bf2f(h0)), l1 = f2bf(v.y - bf2f(h1));
  unsigned l2 = f2bf(v.z - bf2f(h2)), l3 = f2bf(v.w - bf2f(h3));
  hi.x = (h0 & 0xffffu) | (h1 << 16); hi.y = (h2 & 0xffffu) | (h3 << 16);
  lo.x = (l0 & 0xffffu) | (l1 << 16); lo.y = (l2 & 0xffffu) | (l3 << 16);
}

typedef const __attribute__((address_space(1))) void gas_t;
typedef __attribute__((address_space(3))) void las_t;

// ---------------------------------------------------------------------------
// A = softmax(relu(emb @ emb^T)) row-wise. One block per row.
// ---------------------------------------------------------------------------
__global__ __launch_bounds__(256) void build_A(const float* __restrict__ emb,
                                               float* __restrict__ A) {
  __shared__ float sE[N * E];
  __shared__ float sv[N];
  __shared__ float rmax[4], rsum[4];
  const int i = blockIdx.x;
  for (int idx = threadIdx.x; idx < N * E / 4; idx += 256)
    ((float4*)sE)[idx] = ((const float4*)emb)[idx];
  __syncthreads();
  float ei[E];
#pragma unroll
  for (int e = 0; e < E; ++e) ei[e] = sE[i * E + e];
  float mymax = 0.f;
  for (int j = threadIdx.x; j < N; j += 256) {
    float d = 0.f;
#pragma unroll
    for (int e = 0; e < E; ++e) d = fmaf(ei[e], sE[j * E + e], d);
    d = fmaxf(d, 0.f);
    sv[j] = d;
    mymax = fmaxf(mymax, d);
  }
  for (int off = 32; off; off >>= 1) mymax = fmaxf(mymax, __shfl_down(mymax, off));
  const int wid = threadIdx.x >> 6, lid = threadIdx.x & 63;
  if (lid == 0) rmax[wid] = mymax;
  __syncthreads();
  const float m = fmaxf(fmaxf(rmax[0], rmax[1]), fmaxf(rmax[2], rmax[3]));
  float mysum = 0.f;
  for (int j = threadIdx.x; j < N; j += 256) {
    float ev = expf(sv[j] - m);
    sv[j] = ev;
    mysum += ev;
  }
  for (int off = 32; off; off >>= 1) mysum += __shfl_down(mysum, off);
  if (lid == 0) rsum[wid] = mysum;
  __syncthreads();
  const float inv = 1.f / (rsum[0] + rsum[1] + rsum[2] + rsum[3]);
  for (int j = threadIdx.x; j < N; j += 256) A[i * N + j] = sv[j] * inv;
}

// ---------------------------------------------------------------------------
// Split-pack A for the exact S2 gemm: L=(hi,lo,hi), R=(hi,hi,lo) K-triples.
// ---------------------------------------------------------------------------
__global__ __launch_bounds__(256) void pack_split_S(const float* __restrict__ A,
                                                    ushort* __restrict__ L,
                                                    ushort* __restrict__ R) {
  __shared__ float tile[32][33];
  const int bx = blockIdx.x * 32;
  const int by = blockIdx.y * 32;
  const int tx = threadIdx.x & 31;
  const int tg = threadIdx.x >> 5;
#pragma unroll
  for (int p = 0; p < 4; ++p) {
    int ty = tg * 4 + p;
    tile[ty][tx] = A[(size_t)(by + ty) * 1024 + bx + tx];
  }
  __syncthreads();
#pragma unroll
  for (int p = 0; p < 4; ++p) {
    int ty = tg * 4 + p;
    float v = tile[ty][tx];
    unsigned h = f2bf(v);
    unsigned l = f2bf(v - bf2f(h));
    size_t lb = (size_t)(by + ty) * 3072 + 3 * (bx + tx);
    L[lb + 0] = (ushort)h; L[lb + 1] = (ushort)l; L[lb + 2] = (ushort)h;
    float w = tile[tx][ty];
    unsigned hh = f2bf(w);
    unsigned ll = f2bf(w - bf2f(hh));
    size_t rbi = (size_t)(bx + ty) * 3072 + 3 * (by + tx);
    R[rbi + 0] = (ushort)hh; R[rbi + 1] = (ushort)hh; R[rbi + 2] = (ushort)ll;
  }
}

// ---------------------------------------------------------------------------
// fp32 -> bf16 bulk convert (A2 rows 0..1023 = bf16(A))
// ---------------------------------------------------------------------------
__global__ __launch_bounds__(256) void conv_bf16(const float* __restrict__ src,
                                                 ushort* __restrict__ dst) {
  int i = blockIdx.x * 256 + threadIdx.x;
  float4 v = ((const float4*)src)[i];
  ushort4 o;
  o.x = (ushort)f2bf(v.x); o.y = (ushort)f2bf(v.y);
  o.z = (ushort)f2bf(v.z); o.w = (ushort)f2bf(v.w);
  ((ushort4*)dst)[i] = o;
}

// ---------------------------------------------------------------------------
// x/ycov -> bf16 K-major: dst[(off + t*64 + b)][n] = bf16(src[b][t][n])
// ---------------------------------------------------------------------------
__global__ __launch_bounds__(256) void conv_xyK(const float* __restrict__ src,
                                                ushort* __restrict__ dst, int off) {
  int id = blockIdx.x * 256 + threadIdx.x;
  int tb = id >> 10, n = id & 1023;
  int tt = tb >> 6, b = tb & 63;
  dst[(size_t)(off + tb) * 1024 + n] = (ushort)f2bf(src[((size_t)b * T + tt) * 1024 + n]);
}

// ---------------------------------------------------------------------------
// Pre-split s=0 (h-part) weights into panel-major bf16 hi/lo.
// ---------------------------------------------------------------------------
__global__ __launch_bounds__(256) void pack_Wbf(const float* __restrict__ W,
                                                ushort* __restrict__ out,
                                                int CIN, int NC, int xoff) {
  int idx = blockIdx.x * 256 + threadIdx.x;
  int total = 2 * NC * 32;
  if (idx >= total) return;
  int kk = idx & 31;
  int rest = idx >> 5;
  int col = rest % NC;
  int half = rest / NC;
  float v = W[(size_t)(xoff + half * 32 + kk) * NC + col];
  unsigned hi = f2bf(v);
  unsigned lo = f2bf(v - bf2f(hi));
  size_t base = (size_t)(half * 2) * NC * 32;
  out[base + (size_t)col * 32 + kk] = (ushort)hi;
  out[base + (size_t)NC * 32 + (size_t)col * 32 + kk] = (ushort)lo;
}

// ---------------------------------------------------------------------------
// Pack s=1,2 (Ph-part) weights into panel-major fp16.
// ---------------------------------------------------------------------------
__global__ __launch_bounds__(256) void pack_W16(const float* __restrict__ W,
                                                ushort* __restrict__ out,
                                                int CIN, int NC, int xoff) {
  int idx = blockIdx.x * 256 + threadIdx.x;
  int total = 2 * 2 * NC * 32;
  if (idx >= total) return;
  int kk = idx & 31;
  int rest = idx >> 5;
  int col = rest % NC;
  rest /= NC;
  int half = rest & 1;
  int s1 = rest >> 1;
  int s = s1 + 1;
  float v = W[(size_t)(s * CIN + xoff + half * 32 + kk) * NC + col];
  out[(size_t)(s1 * 2 + half) * NC * 32 + (size_t)col * 32 + kk] = f2h(v);
}

// ---------------------------------------------------------------------------
// S2 partials: split-K=4 of the split-bf16 A@A gemm (K=3072 interleaved).
// ---------------------------------------------------------------------------
__global__ __launch_bounds__(256) void gemm_s2p(
    const ushort* __restrict__ L, const ushort* __restrict__ R,
    float* __restrict__ P) {
  __shared__ ushort As[128 * 32];
  __shared__ ushort Bs[128 * 32];
  const int t = threadIdx.x;
  const int wave = t >> 6, lane = t & 63;
  const int bm = blockIdx.y * 128, bn = blockIdx.x * 128;
  const int wm = (wave & 1) * 64, wn = (wave >> 1) * 64;
  float* Pz = P + (size_t)blockIdx.z * 1048576;
  const int kbase = blockIdx.z * 768;

  const ushort* aSrc[2]; const ushort* bSrc[2];
  ushort* aDst[2]; ushort* bDst[2];
#pragma unroll
  for (int u = 0; u < 2; ++u) {
    int idx = wave * 128 + u * 64 + lane;
    int row = idx >> 2;
    int kq = (idx & 3) * 8;
    aSrc[u] = L + (size_t)(bm + row) * 3072 + kq;
    bSrc[u] = R + (size_t)(bn + row) * 3072 + kq;
    aDst[u] = &As[(wave * 128 + u * 64) * 8];
    bDst[u] = &Bs[(wave * 128 + u * 64) * 8];
  }
  const int lr = lane & 15;
  const int lk = (lane >> 4) * 8;
  f32x4 acc[4][4];
#pragma unroll
  for (int i = 0; i < 4; ++i)
#pragma unroll
    for (int j = 0; j < 4; ++j) acc[i][j] = {0.f, 0.f, 0.f, 0.f};

  for (int k0 = kbase; k0 < kbase + 768; k0 += 32) {
#pragma unroll
    for (int u = 0; u < 2; ++u) {
      __builtin_amdgcn_global_load_lds((gas_t*)(aSrc[u] + k0), (las_t*)aDst[u], 16, 0, 0);
      __builtin_amdgcn_global_load_lds((gas_t*)(bSrc[u] + k0), (las_t*)bDst[u], 16, 0, 0);
    }
    __syncthreads();
    short8 a[4], b[4];
#pragma unroll
    for (int i = 0; i < 4; ++i) a[i] = *(const short8*)&As[(wm + i * 16 + lr) * 32 + lk];
#pragma unroll
    for (int j = 0; j < 4; ++j) b[j] = *(const short8*)&Bs[(wn + j * 16 + lr) * 32 + lk];
#pragma unroll
    for (int i = 0; i < 4; ++i)
#pragma unroll
      for (int j = 0; j < 4; ++j)
        acc[i][j] = __builtin_amdgcn_mfma_f32_16x16x32_bf16(a[i], b[j], acc[i][j], 0, 0, 0);
    __syncthreads();
  }
  const int cr = (lane >> 4) * 4;
  const int cc = lane & 15;
#pragma unroll
  for (int i = 0; i < 4; ++i)
#pragma unroll
    for (int j = 0; j < 4; ++j) {
      int gm = bm + wm + i * 16 + cr;
      int gn = bn + wn + j * 16 + cc;
#pragma unroll
      for (int r = 0; r < 4; ++r)
        Pz[(size_t)(gm + r) * 1024 + gn] = acc[i][j][r];
    }
}

// ---------------------------------------------------------------------------
// Combine S2 partials: v = 2*sum - I, write bf16 into A2 rows 1024..2047.
// ---------------------------------------------------------------------------
__global__ __launch_bounds__(256) void comb_s2(const float* __restrict__ P,
                                               ushort* __restrict__ A2) {
  int idx = blockIdx.x * 256 + threadIdx.x;
  float4 a = ((const float4*)P)[idx];
  float4 b = ((const float4*)(P + 1048576))[idx];
  float4 c = ((const float4*)(P + 2097152))[idx];
  float4 d = ((const float4*)(P + 3145728))[idx];
  int base = idx << 2;
  int m = base >> 10, c0 = base & 1023;
  float v0 = 2.f * (a.x + b.x + c.x + d.x) - (m == c0 + 0 ? 1.f : 0.f);
  float v1 = 2.f * (a.y + b.y + c.y + d.y) - (m == c0 + 1 ? 1.f : 0.f);
  float v2 = 2.f * (a.z + b.z + c.z + d.z) - (m == c0 + 2 ? 1.f : 0.f);
  float v3 = 2.f * (a.w + b.w + c.w + d.w) - (m == c0 + 3 ? 1.f : 0.f);
  ushort4 o;
  o.x = (ushort)f2bf(v0); o.y = (ushort)f2bf(v1);
  o.z = (ushort)f2bf(v2); o.w = (ushort)f2bf(v3);
  ((ushort4*)(A2 + 1048576))[idx] = o;
}

// ---------------------------------------------------------------------------
// Propagation GEMM (pure bf16 B^T, m97 form): C[2048][cols] = A2 @ Bt^T.
// CMODE 0: C1f row-major stride n1 (fp32, 2-D grid).
// CMODE 1: C1h fp16 state layout [half][(b,n)][j]; 1-D grid with XCD swizzle
//          (each XCD owns 4 bn-tiles -> B slice ~1 MB, L2-resident).
// Fold cols >= n1 -> C2 (fp32).
// ---------------------------------------------------------------------------
template <int CMODE>
__global__ __launch_bounds__(256) void gemm_bt(
    const ushort* __restrict__ A2, const ushort* __restrict__ Bt, int n1,
    ushort* __restrict__ C1h, float* __restrict__ C1f, float* __restrict__ C2) {
  __shared__ ushort As[2][128 * 32];
  __shared__ ushort Bs[2][128 * 32];
  const int t = threadIdx.x;
  const int wave = t >> 6, lane = t & 63;
  int bxi, byi;
  if (CMODE == 0) {
    bxi = blockIdx.x; byi = blockIdx.y;
  } else {
    int lin = blockIdx.x;
    if (lin < 512) {
      bxi = (lin & 7) * 4 + ((lin >> 3) & 3);
      byi = lin >> 5;
    } else {
      bxi = 32; byi = lin - 512;
    }
  }
  const int bm = byi * 128, bn = bxi * 128;
  const int wm = (wave & 1) * 64, wn = (wave >> 1) * 64;

  const ushort* aSrc[2]; const ushort* bSrc[2];
  ushort* aDst[2][2]; ushort* bDst[2][2];
#pragma unroll
  for (int u = 0; u < 2; ++u) {
    int idx = wave * 128 + u * 64 + lane;
    int row = idx >> 2;
    int kq = (idx & 3) * 8;
    aSrc[u] = A2 + (size_t)(bm + row) * 1024 + kq;
    bSrc[u] = Bt + (size_t)(bn + row) * 1024 + kq;
#pragma unroll
    for (int p = 0; p < 2; ++p) {
      aDst[p][u] = &As[p][(wave * 128 + u * 64) * 8];
      bDst[p][u] = &Bs[p][(wave * 128 + u * 64) * 8];
    }
  }
  const int lr = lane & 15, lk = (lane >> 4) * 8;
  int aOff[4], bOff[4];
#pragma unroll
  for (int i = 0; i < 4; ++i) {
    aOff[i] = (wm + i * 16 + lr) * 32 + lk;
    bOff[i] = (wn + i * 16 + lr) * 32 + lk;
  }
  f32x4 acc[4][4];
#pragma unroll
  for (int i = 0; i < 4; ++i)
#pragma unroll
    for (int j = 0; j < 4; ++j) acc[i][j] = {0.f, 0.f, 0.f, 0.f};

  for (int k0 = 0; k0 < 1024; k0 += 64) {
#pragma unroll
    for (int p = 0; p < 2; ++p)
#pragma unroll
      for (int u = 0; u < 2; ++u) {
        __builtin_amdgcn_global_load_lds((gas_t*)(aSrc[u] + k0 + p * 32),
                                         (las_t*)aDst[p][u], 16, 0, 0);
        __builtin_amdgcn_global_load_lds((gas_t*)(bSrc[u] + k0 + p * 32),
                                         (las_t*)bDst[p][u], 16, 0, 0);
      }
    __syncthreads();
#pragma unroll
    for (int p = 0; p < 2; ++p) {
      short8 a[4], b[4];
#pragma unroll
      for (int i = 0; i < 4; ++i) a[i] = *(const short8*)&As[p][aOff[i]];
#pragma unroll
      for (int j = 0; j < 4; ++j) b[j] = *(const short8*)&Bs[p][bOff[j]];
#pragma unroll
      for (int i = 0; i < 4; ++i)
#pragma unroll
        for (int j = 0; j < 4; ++j)
          acc[i][j] = __builtin_amdgcn_mfma_f32_16x16x32_bf16(a[i], b[j], acc[i][j], 0, 0, 0);
    }
    __syncthreads();
  }

  const int cr = (lane >> 4) * 4;
  const int cc = lane & 15;
#pragma unroll
  for (int i = 0; i < 4; ++i) {
#pragma unroll
    for (int j = 0; j < 4; ++j) {
      int gm = bm + wm + i * 16 + cr;
      int gn = bn + wn + j * 16 + cc;
      if (gn < n1) {
        if (CMODE == 0) {
          float* p = C1f + (size_t)gm * n1 + gn;
#pragma unroll
          for (int r = 0; r < 4; ++r) p[(size_t)r * n1] = acc[i][j][r];
        } else {
          int half = gm >> 10, nn = gm & 1023;
          ushort* p = C1h + (size_t)half * NBH +
                      ((size_t)(gn >> 6) * 1024 + nn) * 64 + (gn & 63);
#pragma unroll
          for (int r = 0; r < 4; ++r) p[(size_t)r * 64] = f2h(acc[i][j][r]);
        }
      } else if (C2 != nullptr && gn < n1 + 64) {
        float* p = C2 + (size_t)gm * 64 + (gn - n1);
#pragma unroll
        for (int r = 0; r < 4; ++r) p[(size_t)r * 64] = acc[i][j][r];
      }
    }
  }
}

// ---------------------------------------------------------------------------
// Gate: zr = sigmoid( s0-GEMM(split-bf16 exact h) + s1,2-GEMM(fp16 Ph, f16 MFMA)
//                     + exact fp32 x-terms + bias ). Writes zh, r, Btz.
// ---------------------------------------------------------------------------
template <int NX>
__global__ __launch_bounds__(256, 4) void gate_mfma(
    const float* __restrict__ hmat, const ushort* __restrict__ Ph16,
    const ushort* __restrict__ Wbf, const ushort* __restrict__ W16,
    const float* __restrict__ Wf, const float* __restrict__ bias,
    const float* __restrict__ xb0, int xbs0, const float* __restrict__ xp0, int xs0,
    const float* __restrict__ xb1, int xbs1, const float* __restrict__ xp1, int xs1,
    float* __restrict__ zh, float* __restrict__ rbuf, ushort* __restrict__ Btz) {
  constexpr int CIN = NX + 64;
  __shared__ ushort smem[12288];
  ushort* Ah = smem;
  ushort* Al = smem + 2048;
  ushort* Bh = smem + 4096;
  ushort* Bl = smem + 8192;
  ushort* A16 = smem;
  ushort* B16 = smem + 4096;
  ushort* transT = smem;
  __shared__ float sxv[3][2][64];
  __shared__ float sWx[3][2][128];
  const int t = threadIdx.x;
  const int wave = t >> 6, lane = t & 63;
  const int bm = blockIdx.x * 64;
  const int wm = (wave & 1) * 32, wn = (wave >> 1) * 64;
  const int lr = lane & 15, lk = (lane >> 4) * 8;

  if (t < 64) {
    int grow = bm + t;
    int n = grow & 1023, b = grow >> 10;
    sxv[0][0][t] = xb0[(size_t)b * xbs0 + n];
    sxv[1][0][t] = xp0[(size_t)n * xs0 + b];
    sxv[2][0][t] = xp0[(size_t)1024 * xs0 + (size_t)n * xs0 + b];
    if (NX == 2) {
      sxv[0][1][t] = xb1[(size_t)b * xbs1 + n];
      sxv[1][1][t] = xp1[(size_t)n * xs1 + b];
      sxv[2][1][t] = xp1[(size_t)1024 * xs1 + (size_t)n * xs1 + b];
    }
  } else if (t < 192) {
    int col = t - 64;
#pragma unroll
    for (int s = 0; s < 3; ++s)
#pragma unroll
      for (int f = 0; f < NX; ++f)
        sWx[s][f][col] = Wf[(size_t)(s * CIN + f) * 128 + col];
  }

  int arow[2], ajq[2];
#pragma unroll
  for (int p = 0; p < 2; ++p) {
    int f = p * 256 + t;
    arow[p] = f >> 3;
    ajq[p] = (f & 7) * 4;
  }
  const int hrow = t >> 2, hjq = (t & 3) * 8;

  float4 pf[2];
#pragma unroll
  for (int p = 0; p < 2; ++p)
    pf[p] = *(const float4*)(hmat + (size_t)(bm + arow[p]) * 64 + ajq[p]);
  uint4 px;

  f32x4 acc[2][4];
#pragma unroll
  for (int i = 0; i < 2; ++i)
#pragma unroll
    for (int j = 0; j < 4; ++j) acc[i][j] = {0.f, 0.f, 0.f, 0.f};

  // ---- phase 1: s=0, exact split-bf16, 2 halves ----
#pragma unroll
  for (int half = 0; half < 2; ++half) {
#pragma unroll
    for (int p = 0; p < 2; ++p) {
      uint2 hi, lo;
      split4(pf[p], hi, lo);
      *(uint2*)&Ah[arow[p] * 32 + ajq[p]] = hi;
      *(uint2*)&Al[arow[p] * 32 + ajq[p]] = lo;
    }
    const ushort* wph = Wbf + (size_t)(half * 2) * (128 * 32);
    const ushort* wpl = wph + 128 * 32;
#pragma unroll
    for (int u = 0; u < 2; ++u) {
      int idx = wave * 128 + u * 64 + lane;
      __builtin_amdgcn_global_load_lds((gas_t*)(wph + idx * 8), (las_t*)&Bh[idx * 8], 16, 0, 0);
      __builtin_amdgcn_global_load_lds((gas_t*)(wpl + idx * 8), (las_t*)&Bl[idx * 8], 16, 0, 0);
    }
    __syncthreads();
    if (half == 0) {
#pragma unroll
      for (int p = 0; p < 2; ++p)
        pf[p] = *(const float4*)(hmat + (size_t)(bm + arow[p]) * 64 + 32 + ajq[p]);
    } else {
      px = *(const uint4*)(Ph16 + (size_t)(bm + hrow) * 64 + hjq);
    }
    short8 ah[2], al[2], bh[4], bl[4];
#pragma unroll
    for (int i = 0; i < 2; ++i) {
      ah[i] = *(const short8*)&Ah[(wm + i * 16 + lr) * 32 + lk];
      al[i] = *(const short8*)&Al[(wm + i * 16 + lr) * 32 + lk];
    }
#pragma unroll
    for (int j = 0; j < 4; ++j) {
      bh[j] = *(const short8*)&Bh[(wn + j * 16 + lr) * 32 + lk];
      bl[j] = *(const short8*)&Bl[(wn + j * 16 + lr) * 32 + lk];
    }
#pragma unroll
    for (int i = 0; i < 2; ++i)
#pragma unroll
      for (int j = 0; j < 4; ++j) {
        acc[i][j] = __builtin_amdgcn_mfma_f32_16x16x32_bf16(ah[i], bh[j], acc[i][j], 0, 0, 0);
        acc[i][j] = __builtin_amdgcn_mfma_f32_16x16x32_bf16(al[i], bh[j], acc[i][j], 0, 0, 0);
        acc[i][j] = __builtin_amdgcn_mfma_f32_16x16x32_bf16(ah[i], bl[j], acc[i][j], 0, 0, 0);
      }
    __syncthreads();
  }

  // ---- phase 2: s=1,2 fp16 Ph, single f16 MFMA ----
  for (int it = 0; it < 4; ++it) {
    const int s1 = it >> 1, half = it & 1;
    *(uint4*)&A16[hrow * 32 + hjq] = px;
    const ushort* w16 = W16 + (size_t)(s1 * 2 + half) * (128 * 32);
#pragma unroll
    for (int u = 0; u < 2; ++u) {
      int idx = wave * 128 + u * 64 + lane;
      __builtin_amdgcn_global_load_lds((gas_t*)(w16 + idx * 8), (las_t*)&B16[idx * 8], 16, 0, 0);
    }
    __syncthreads();
    if (it < 3) {
      const int nit = it + 1;
      const ushort* src = Ph16 + (size_t)(nit >> 1) * NBH;
      px = *(const uint4*)(src + (size_t)(bm + hrow) * 64 + (nit & 1) * 32 + hjq);
    }
    half8 a16[2], b16[4];
#pragma unroll
    for (int i = 0; i < 2; ++i)
      a16[i] = *(const half8*)&A16[(wm + i * 16 + lr) * 32 + lk];
#pragma unroll
    for (int j = 0; j < 4; ++j)
      b16[j] = *(const half8*)&B16[(wn + j * 16 + lr) * 32 + lk];
#pragma unroll
    for (int i = 0; i < 2; ++i)
#pragma unroll
      for (int j = 0; j < 4; ++j)
        acc[i][j] = __builtin_amdgcn_mfma_f32_16x16x32_f16(a16[i], b16[j], acc[i][j], 0, 0, 0);
    __syncthreads();
  }

  const int cr = (lane >> 4) * 4;
  const int cc = lane & 15;
#pragma unroll
  for (int i = 0; i < 2; ++i) {
#pragma unroll
    for (int j = 0; j < 4; ++j) {
      int col = wn + j * 16 + cc;
      float bcol = bias[col];
#pragma unroll
      for (int r = 0; r < 4; ++r) {
        int rowl = wm + i * 16 + cr + r;
        int grow = bm + rowl;
        float v = acc[i][j][r] + bcol;
#pragma unroll
        for (int s = 0; s < 3; ++s)
#pragma unroll
          for (int f = 0; f < NX; ++f)
            v = fmaf(sxv[s][f][rowl], sWx[s][f][col], v);
        float sig = 1.f / (1.f + expf(-v));
        if (col < 64) {
          float zv = sig * hmat[(size_t)grow * 64 + col];
          zh[(size_t)grow * 64 + col] = zv;
          transT[col * 72 + rowl] = (ushort)f2bf(zv);
        } else {
          rbuf[(size_t)grow * 64 + col - 64] = sig;
        }
      }
    }
  }
  __syncthreads();
  const int bq = bm >> 10, nb = bm & 1023;
  for (int idx = t; idx < 512; idx += 256) {
    int j = idx >> 3, ch = idx & 7;
    uint4 v = *(const uint4*)&transT[j * 72 + ch * 8];
    *(uint4*)(Btz + (((size_t)(bq * 64 + j)) << 10) + nb + ch * 8) = v;
  }
}

// ---------------------------------------------------------------------------
// Update: hc = tanh(s0-GEMM(split zh) + s1,2-GEMM(fp16 Pzh) + x-terms + b);
// h = r*h + (1-r)*hc. PROJ=1 fuses go-projection.
// ---------------------------------------------------------------------------
template <int NX, int PROJ>
__global__ __launch_bounds__(256, 4) void upd_mfma(
    float* __restrict__ hmat, const float* __restrict__ zhb, const ushort* __restrict__ Pzh16,
    const ushort* __restrict__ Wbf, const ushort* __restrict__ W16,
    const float* __restrict__ Wf, const float* __restrict__ bias,
    const float* __restrict__ xb0, int xbs0, const float* __restrict__ xp0, int xs0,
    const float* __restrict__ xb1, int xbs1, const float* __restrict__ xp1, int xs1,
    const float* __restrict__ rbuf, ushort* __restrict__ Bth,
    const float* __restrict__ pW, const float* __restrict__ pb,
    float* __restrict__ gobuf, float* __restrict__ outp, int tstep) {
  constexpr int CIN = NX + 64;
  __shared__ ushort smem[8192];
  ushort* Ah = smem;
  ushort* Al = smem + 2048;
  ushort* Bh = smem + 4096;
  ushort* Bl = smem + 6144;
  ushort* A16 = smem;
  ushort* B16 = smem + 4096;
  ushort* transT = smem;
  __shared__ float sxv[3][2][64];
  __shared__ float sWx[3][2][64];
  __shared__ float part[2][64];
  const int t = threadIdx.x;
  const int wave = t >> 6, lane = t & 63;
  const int bm = blockIdx.x * 64;
  const int wm = (wave & 1) * 32, wn = (wave >> 1) * 32;
  const int lr = lane & 15, lk = (lane >> 4) * 8;

  if (t < 64) {
    int grow = bm + t;
    int n = grow & 1023, b = grow >> 10;
    sxv[0][0][t] = xb0[(size_t)b * xbs0 + n];
    sxv[1][0][t] = xp0[(size_t)n * xs0 + b];
    sxv[2][0][t] = xp0[(size_t)1024 * xs0 + (size_t)n * xs0 + b];
    if (NX == 2) {
      sxv[0][1][t] = xb1[(size_t)b * xbs1 + n];
      sxv[1][1][t] = xp1[(size_t)n * xs1 + b];
      sxv[2][1][t] = xp1[(size_t)1024 * xs1 + (size_t)n * xs1 + b];
    }
  } else if (t < 128) {
    int col = t - 64;
#pragma unroll
    for (int s = 0; s < 3; ++s)
#pragma unroll
      for (int f = 0; f < NX; ++f)
        sWx[s][f][col] = Wf[(size_t)(s * CIN + f) * 64 + col];
  }

  int arow[2], ajq[2];
#pragma unroll
  for (int p = 0; p < 2; ++p) {
    int f = p * 256 + t;
    arow[p] = f >> 3;
    ajq[p] = (f & 7) * 4;
  }
  const int hrow = t >> 2, hjq = (t & 3) * 8;

  float4 pf[2];
#pragma unroll
  for (int p = 0; p < 2; ++p)
    pf[p] = *(const float4*)(zhb + (size_t)(bm + arow[p]) * 64 + ajq[p]);
  uint4 px;

  f32x4 acc[2][2];
#pragma unroll
  for (int i = 0; i < 2; ++i)
#pragma unroll
    for (int j = 0; j < 2; ++j) acc[i][j] = {0.f, 0.f, 0.f, 0.f};

  // ---- phase 1: s=0 exact split ----
#pragma unroll
  for (int half = 0; half < 2; ++half) {
#pragma unroll
    for (int p = 0; p < 2; ++p) {
      uint2 hi, lo;
      split4(pf[p], hi, lo);
      *(uint2*)&Ah[arow[p] * 32 + ajq[p]] = hi;
      *(uint2*)&Al[arow[p] * 32 + ajq[p]] = lo;
    }
    const ushort* wph = Wbf + (size_t)(half * 2) * (64 * 32);
    const ushort* wpl = wph + 64 * 32;
    {
      int idx = wave * 64 + lane;
      __builtin_amdgcn_global_load_lds((gas_t*)(wph + idx * 8), (las_t*)&Bh[idx * 8], 16, 0, 0);
      __builtin_amdgcn_global_load_lds((gas_t*)(wpl + idx * 8), (las_t*)&Bl[idx * 8], 16, 0, 0);
    }
    __syncthreads();
    if (half == 0) {
#pragma unroll
      for (int p = 0; p < 2; ++p)
        pf[p] = *(const float4*)(zhb + (size_t)(bm + arow[p]) * 64 + 32 + ajq[p]);
    } else {
      px = *(const uint4*)(Pzh16 + (size_t)(bm + hrow) * 64 + hjq);
    }
    short8 ah[2], al[2], bh[2], bl[2];
#pragma unroll
    for (int i = 0; i < 2; ++i) {
      ah[i] = *(const short8*)&Ah[(wm + i * 16 + lr) * 32 + lk];
      al[i] = *(const short8*)&Al[(wm + i * 16 + lr) * 32 + lk];
    }
#pragma unroll
    for (int j = 0; j < 2; ++j) {
      bh[j] = *(const short8*)&Bh[(wn + j * 16 + lr) * 32 + lk];
      bl[j] = *(const short8*)&Bl[(wn + j * 16 + lr) * 32 + lk];
    }
#pragma unroll
    for (int i = 0; i < 2; ++i)
#pragma unroll
      for (int j = 0; j < 2; ++j) {
        acc[i][j] = __builtin_amdgcn_mfma_f32_16x16x32_bf16(ah[i], bh[j], acc[i][j], 0, 0, 0);
        acc[i][j] = __builtin_amdgcn_mfma_f32_16x16x32_bf16(al[i], bh[j], acc[i][j], 0, 0, 0);
        acc[i][j] = __builtin_amdgcn_mfma_f32_16x16x32_bf16(ah[i], bl[j], acc[i][j], 0, 0, 0);
      }
    __syncthreads();
  }

  // ---- phase 2: s=1,2 fp16 ----
  for (int it = 0; it < 4; ++it) {
    const int s1 = it >> 1, half = it & 1;
    *(uint4*)&A16[hrow * 32 + hjq] = px;
    const ushort* w16 = W16 + (size_t)(s1 * 2 + half) * (64 * 32);
    {
      int idx = wave * 64 + lane;
      __builtin_amdgcn_global_load_lds((gas_t*)(w16 + idx * 8), (las_t*)&B16[idx * 8], 16, 0, 0);
    }
    __syncthreads();
    if (it < 3) {
      const int nit = it + 1;
      const ushort* src = Pzh16 + (size_t)(nit >> 1) * NBH;
      px = *(const uint4*)(src + (size_t)(bm + hrow) * 64 + (nit & 1) * 32 + hjq);
    }
    half8 a16[2], b16[2];
#pragma unroll
    for (int i = 0; i < 2; ++i)
      a16[i] = *(const half8*)&A16[(wm + i * 16 + lr) * 32 + lk];
#pragma unroll
    for (int j = 0; j < 2; ++j)
      b16[j] = *(const half8*)&B16[(wn + j * 16 + lr) * 32 + lk];
#pragma unroll
    for (int i = 0; i < 2; ++i)
#pragma unroll
      for (int j = 0; j < 2; ++j)
        acc[i][j] = __builtin_amdgcn_mfma_f32_16x16x32_f16(a16[i], b16[j], acc[i][j], 0, 0, 0);
    __syncthreads();
  }

  const int cr = (lane >> 4) * 4;
  const int cc = lane & 15;
  float psv[2][4];
#pragma unroll
  for (int i = 0; i < 2; ++i)
#pragma unroll
    for (int r = 0; r < 4; ++r) psv[i][r] = 0.f;

#pragma unroll
  for (int i = 0; i < 2; ++i) {
#pragma unroll
    for (int j = 0; j < 2; ++j) {
      int col = wn + j * 16 + cc;
      float bcol = bias[col];
      float pwc = PROJ ? pW[col] : 0.f;
#pragma unroll
      for (int r = 0; r < 4; ++r) {
        int rowl = wm + i * 16 + cr + r;
        int grow = bm + rowl;
        float v = acc[i][j][r] + bcol;
#pragma unroll
        for (int s = 0; s < 3; ++s)
#pragma unroll
          for (int f = 0; f < NX; ++f)
            v = fmaf(sxv[s][f][rowl], sWx[s][f][col], v);
        float hc = tanhf(v);
        size_t idx = (size_t)grow * 64 + col;
        float rr = rbuf[idx];
        float ho = hmat[idx];
        float o = rr * ho + (1.f - rr) * hc;
        hmat[idx] = o;
        transT[col * 72 + rowl] = (ushort)f2bf(o);
        if (PROJ) psv[i][r] += o * pwc;
      }
    }
  }
  if (PROJ) {
#pragma unroll
    for (int i = 0; i < 2; ++i)
#pragma unroll
      for (int r = 0; r < 4; ++r)
#pragma unroll
        for (int off = 8; off; off >>= 1)
          psv[i][r] += __shfl_down(psv[i][r], off, 16);
    if (cc == 0) {
#pragma unroll
      for (int i = 0; i < 2; ++i)
#pragma unroll
        for (int r = 0; r < 4; ++r)
          part[wn >> 5][wm + i * 16 + cr + r] = psv[i][r];
    }
  }
  __syncthreads();
  const int bq = bm >> 10, nb = bm & 1023;
  for (int idx = t; idx < 512; idx += 256) {
    int j = idx >> 3, ch = idx & 7;
    uint4 v = *(const uint4*)&transT[j * 72 + ch * 8];
    *(uint4*)(Bth + (((size_t)(bq * 64 + j)) << 10) + nb + ch * 8) = v;
  }
  if (PROJ && t < 64) {
    int grow = bm + t;
    int n = grow & 1023, b = grow >> 10;
    float g = part[0][t] + part[1][t] + pb[0];
    gobuf[grow] = g;
    outp[((size_t)b * HOR + tstep) * N + n] = g;
    Bth[((size_t)(4096 + b)) * 1024 + n] = (ushort)f2bf(g);
  }
}

// ---------------------------------------------------------------------------
extern "C" void kernel_launch(void* const* d_in, const int* in_sizes, int n_in,
                              void* d_out, int out_size, void* d_ws, size_t ws_size,
                              hipStream_t stream) {
  const float* x    = (const float*)d_in[0];
  const float* ycov = (const float*)d_in[1];
  const float* emb  = (const float*)d_in[2];
  const float* egW  = (const float*)d_in[3];
  const float* egb  = (const float*)d_in[4];
  const float* euW  = (const float*)d_in[5];
  const float* eub  = (const float*)d_in[6];
  const float* dgW  = (const float*)d_in[7];
  const float* dgb  = (const float*)d_in[8];
  const float* duW  = (const float*)d_in[9];
  const float* dub  = (const float*)d_in[10];
  const float* pW   = (const float*)d_in[11];
  const float* pb   = (const float*)d_in[12];
  float* out = (float*)d_out;
  float* ws  = (float*)d_ws;

  float* Amat = ws + A_off;
  float* Pxy  = ws + Pxy_off;
  float* hmat = ws + h_off;
  ushort* Ph16 = (ushort*)(ws + Ph_off);
  float* zh   = ws + zh_off;
  float* rb   = ws + r_off;
  float* gob  = ws + go_off;
  float* Pgo  = ws + Pgo_off;
  ushort* A2   = (ushort*)(ws + A2_off);
  ushort* Bth  = (ushort*)(ws + Bth_off);
  ushort* Btz  = (ushort*)(ws + Btz_off);
  ushort* xyK  = (ushort*)(ws + xyK_off);
  ushort* AspL = (ushort*)(ws + zh_off);
  ushort* AspR = (ushort*)(ws + r_off);
  float*  Pp   = ws + Ph_off;              // S2 partials alias (precompute only)
  ushort* WB   = (ushort*)(ws + wp_off);
  ushort* WbfGE = WB;
  ushort* WbfGD = WB + 16384;
  ushort* WbfUE = WB + 32768;
  ushort* WbfUD = WB + 40960;
  ushort* W16GE = WB + 49152;
  ushort* W16GD = WB + 65536;
  ushort* W16UE = WB + 81920;
  ushort* W16UD = WB + 90112;

  // ---- precompute ----
  build_A<<<N, 256, 0, stream>>>(emb, Amat);
  pack_split_S<<<dim3(32, 32), 256, 0, stream>>>(Amat, AspL, AspR);
  gemm_s2p<<<dim3(8, 8, 4), 256, 0, stream>>>(AspL, AspR, Pp);
  comb_s2<<<1024, 256, 0, stream>>>(Pp, A2);
  conv_bf16<<<1024, 256, 0, stream>>>(Amat, A2);
  conv_xyK<<<3072, 256, 0, stream>>>(x, xyK, 0);
  conv_xyK<<<3072, 256, 0, stream>>>(ycov, xyK, 768);
  pack_Wbf<<<32, 256, 0, stream>>>(egW, WbfGE, 65, 128, 1);
  pack_Wbf<<<32, 256, 0, stream>>>(dgW, WbfGD, 66, 128, 2);
  pack_Wbf<<<16, 256, 0, stream>>>(euW, WbfUE, 65, 64, 1);
  pack_Wbf<<<16, 256, 0, stream>>>(duW, WbfUD, 66, 64, 2);
  pack_W16<<<64, 256, 0, stream>>>(egW, W16GE, 65, 128, 1);
  pack_W16<<<64, 256, 0, stream>>>(dgW, W16GD, 66, 128, 2);
  pack_W16<<<32, 256, 0, stream>>>(euW, W16UE, 65, 64, 1);
  pack_W16<<<32, 256, 0, stream>>>(duW, W16UD, 66, 64, 2);
  gemm_bt<0><<<dim3(12, 16), 256, 0, stream>>>(A2, xyK, 1536, nullptr, Pxy, nullptr);
  (void)hipMemsetAsync(hmat, 0, NBH * sizeof(float), stream);
  (void)hipMemsetAsync(Ph16, 0, 2 * NBH * sizeof(ushort), stream);
  (void)hipMemsetAsync(gob, 0, 65536 * sizeof(float), stream);
  (void)hipMemsetAsync(Bth + (size_t)4096 * 1024, 0, 128 * 1024 * sizeof(ushort), stream);

  // ---- encoder ----
  for (int t = 0; t < T; ++t) {
    if (t > 0)  // t=0: h=0 so Ph=0 (memset)
      gemm_bt<1><<<512, 256, 0, stream>>>(A2, Bth, 4096, Ph16, nullptr, nullptr);
    gate_mfma<1><<<1024, 256, 0, stream>>>(hmat, Ph16, WbfGE, W16GE, egW, egb,
                                           x + t * 1024, T * 1024, Pxy + t * 64, 1536,
                                           nullptr, 0, nullptr, 0, zh, rb, Btz);
    if (t > 0)  // t=0: zh = z*0 = 0, so P(zh)=0
      gemm_bt<1><<<512, 256, 0, stream>>>(A2, Btz, 4096, Ph16, nullptr, nullptr);
    upd_mfma<1, 0><<<1024, 256, 0, stream>>>(hmat, zh, Ph16, WbfUE, W16UE, euW, eub,
                                             x + t * 1024, T * 1024, Pxy + t * 64, 1536,
                                             nullptr, 0, nullptr, 0, rb, Bth,
                                             nullptr, nullptr, nullptr, nullptr, 0);
  }

  // ---- decoder ----
  for (int t = 0; t < HOR; ++t) {
    gemm_bt<1><<<528, 256, 0, stream>>>(A2, Bth, 4096, Ph16, nullptr, Pgo);
    gate_mfma<2><<<1024, 256, 0, stream>>>(hmat, Ph16, WbfGD, W16GD, dgW, dgb,
                                           gob, 1024, Pgo, 64,
                                           ycov + t * 1024, HOR * 1024,
                                           Pxy + 768 + t * 64, 1536, zh, rb, Btz);
    gemm_bt<1><<<512, 256, 0, stream>>>(A2, Btz, 4096, Ph16, nullptr, nullptr);
    upd_mfma<2, 1><<<1024, 256, 0, stream>>>(hmat, zh, Ph16, WbfUD, W16UD, duW, dub,
                                             gob, 1024, Pgo, 64,
                                             ycov + t * 1024, HOR * 1024,
                                             Pxy + 768 + t * 64, 1536,
                                             rb, Bth, pW, pb, gob, out, t);
  }
}